// Round 2
// baseline (287.601 us; speedup 1.0000x reference)
//
#include <hip/hip_runtime.h>

// Sinkhorn top-K stabilization.
// B=512 rows, N=2048 scores, 2 anchors (0,1), EPS=0.1, 200 iterations.
//
// Math (derived from the reference scan body):
//   Chat_a[n] = (s[n]-a)^2 / Cmax   (Cmax = global max over all rows/anchors)
//   f[n]  = EPS*log(1/N)   - EPS*LSE_a((g_a - Chat_a[n])/EPS)     (f-independent)
//   g_a   = EPS*log(nu_a)  - EPS*LSE_n((f[n] - Chat_a[n])/EPS)
//   P_a[n] = exp((f[n] + g_a - Chat_a[n])/EPS)
//
// exp(x/EPS) = exp2(x * C1), EPS*ln(S) = C3 * log2(S).
// Hardware transcendentals: v_exp_f32 / v_log_f32 via amdgcn builtins
// (plain __exp2f/__log2f collide with glibc math.h prototypes).

#define EXP2(x) __builtin_amdgcn_exp2f(x)
#define LOG2(x) __builtin_amdgcn_logf(x)

constexpr int B = 512;
constexpr int N = 2048;
constexpr int MAX_ITER = 200;
constexpr int TPB = 256;
constexpr int VPT = N / TPB; // 8 values per thread

#define C1f    14.426950408889634f     // log2(e)/EPS
#define C3f    0.069314718055994531f   // EPS*ln(2)
#define C_FMU  (-0.76246189861593985f) // EPS*log(1/2048)
#define C_NU0  (-0.13862943611198906f) // EPS*log(512/2048)
#define C_NU1  (-0.028768207245178092f)// EPS*log(1536/2048)

__global__ void k_max(const float* __restrict__ s, unsigned* __restrict__ ws) {
    __shared__ float red[TPB / 64];
    int idx = blockIdx.x * blockDim.x + threadIdx.x;
    int stride = gridDim.x * blockDim.x;
    float m = 0.f;
    for (int i = idx; i < B * N; i += stride) {
        float x = s[i];
        float xm = x - 1.f;
        m = fmaxf(m, fmaxf(x * x, xm * xm));
    }
#pragma unroll
    for (int off = 32; off; off >>= 1) m = fmaxf(m, __shfl_xor(m, off));
    int lane = threadIdx.x & 63, wid = threadIdx.x >> 6;
    if (lane == 0) red[wid] = m;
    __syncthreads();
    if (threadIdx.x == 0) {
        float mm = red[0];
        for (int w = 1; w < TPB / 64; ++w) mm = fmaxf(mm, red[w]);
        atomicMax(ws, __float_as_uint(mm)); // all values >= 0: uint order == float order
    }
}

__launch_bounds__(TPB)
__global__ void k_sink(const float* __restrict__ scores,
                       const unsigned* __restrict__ wsmax,
                       float* __restrict__ out) {
    const int b = blockIdx.x;
    const int tid = threadIdx.x;
    const int lane = tid & 63, wid = tid >> 6;

    __shared__ float lmax[2][8]; // [iter parity][wave*2 + anchor]
    __shared__ float lsum[2][8];

    const float invC = 1.0f / __uint_as_float(*wsmax);

    // Load this thread's 8 contiguous scores (two float4s), build costs in regs.
    const float4* rv = (const float4*)(scores + b * N + tid * VPT);
    float4 sa = rv[0], sb = rv[1];
    float sv[VPT] = {sa.x, sa.y, sa.z, sa.w, sb.x, sb.y, sb.z, sb.w};
    float c0[VPT], c1[VPT], f[VPT];
#pragma unroll
    for (int i = 0; i < VPT; ++i) {
        float s = sv[i];
        float t = s - 1.f;
        c0[i] = s * s * invC;
        c1[i] = t * t * invC;
    }

    float v0 = 1.f, v1 = 1.f; // g0 = ones

    for (int it = 0; it < MAX_ITER; ++it) {
        const int p = it & 1;
        // ---- f update (elementwise) + local max of (f - Chat_a) ----
        float m0 = -3.0e38f, m1 = -3.0e38f;
#pragma unroll
        for (int i = 0; i < VPT; ++i) {
            float d0 = v0 - c0[i];
            float d1 = v1 - c1[i];
            float m = fmaxf(d0, d1);
            float dd = fabsf(d0 - d1);
            // EPS*LSE = m + EPS*log1p(exp(-dd/EPS))
            float e = EXP2(-dd * C1f);
            float fn = C_FMU - m - C3f * LOG2(1.f + e);
            f[i] = fn;
            m0 = fmaxf(m0, fn - c0[i]);
            m1 = fmaxf(m1, fn - c1[i]);
        }
        // ---- block max reduce (both anchors) ----
#pragma unroll
        for (int off = 32; off; off >>= 1) {
            m0 = fmaxf(m0, __shfl_xor(m0, off));
            m1 = fmaxf(m1, __shfl_xor(m1, off));
        }
        if (lane == 0) { lmax[p][wid * 2] = m0; lmax[p][wid * 2 + 1] = m1; }
        __syncthreads();
        m0 = fmaxf(fmaxf(lmax[p][0], lmax[p][2]), fmaxf(lmax[p][4], lmax[p][6]));
        m1 = fmaxf(fmaxf(lmax[p][1], lmax[p][3]), fmaxf(lmax[p][5], lmax[p][7]));
        // ---- sum of exp ----
        float s0 = 0.f, s1 = 0.f;
#pragma unroll
        for (int i = 0; i < VPT; ++i) {
            s0 += EXP2((f[i] - c0[i] - m0) * C1f);
            s1 += EXP2((f[i] - c1[i] - m1) * C1f);
        }
#pragma unroll
        for (int off = 32; off; off >>= 1) {
            s0 += __shfl_xor(s0, off);
            s1 += __shfl_xor(s1, off);
        }
        if (lane == 0) { lsum[p][wid * 2] = s0; lsum[p][wid * 2 + 1] = s1; }
        __syncthreads();
        s0 = (lsum[p][0] + lsum[p][2]) + (lsum[p][4] + lsum[p][6]);
        s1 = (lsum[p][1] + lsum[p][3]) + (lsum[p][5] + lsum[p][7]);
        // ---- g update (uniform across block) ----
        v0 = C_NU0 - m0 - C3f * LOG2(s0);
        v1 = C_NU1 - m1 - C3f * LOG2(s1);
    }

    // ---- output P = exp2((f + g_a - Chat_a) * C1) ----
    float* o0 = out + b * 2 * N + tid * VPT;
    float* o1 = o0 + N;
    float r0[VPT], r1[VPT];
#pragma unroll
    for (int i = 0; i < VPT; ++i) {
        r0[i] = EXP2((f[i] - c0[i] + v0) * C1f);
        r1[i] = EXP2((f[i] - c1[i] + v1) * C1f);
    }
    ((float4*)o0)[0] = make_float4(r0[0], r0[1], r0[2], r0[3]);
    ((float4*)o0)[1] = make_float4(r0[4], r0[5], r0[6], r0[7]);
    ((float4*)o1)[0] = make_float4(r1[0], r1[1], r1[2], r1[3]);
    ((float4*)o1)[1] = make_float4(r1[4], r1[5], r1[6], r1[7]);
}

extern "C" void kernel_launch(void* const* d_in, const int* in_sizes, int n_in,
                              void* d_out, int out_size, void* d_ws, size_t ws_size,
                              hipStream_t stream) {
    const float* scores = (const float*)d_in[0];
    float* out = (float*)d_out;
    unsigned* wsu = (unsigned*)d_ws;

    (void)hipMemsetAsync(wsu, 0, sizeof(unsigned), stream); // zero the max accumulator
    k_max<<<512, TPB, 0, stream>>>(scores, wsu);
    k_sink<<<B, TPB, 0, stream>>>(scores, wsu, out);
}

// Round 3
// 114.953 us; speedup vs baseline: 2.5019x; 2.5019x over previous
//
#include <hip/hip_runtime.h>

// Sinkhorn top-K stabilization — multiplicative domain.
// B=512 rows, N=2048 scores, anchors {0,1}, EPS=0.1, 200 iterations.
//
// Derivation (f-update is independent of old f; validated in round 2):
//   phi[n]  = (1/N) / (g0*E0[n] + g1*E1[n]),  E_a[n] = exp(-Chat_a[n]/EPS)
//   gam_a   = (nu_a*N) / T_a,  T_a = sum_n E_a[n] / (g0*E0[n]+g1*E1[n])
//   identity: g0*T0 + g1*T1 = N exactly  =>  only T0 needs reducing.
//   P_a[n]  = (gam_a/N) * E_a[n] * r[n],  r[n] = 1/(g0*E0+g1*E1) from the
//             LAST f-update (i.e. gamma values BEFORE the final g-update).

#define EXP2(x) __builtin_amdgcn_exp2f(x)
#define RCP(x)  __builtin_amdgcn_rcpf(x)

constexpr int B = 512;
constexpr int N = 2048;
constexpr int MAX_ITER = 200;
constexpr int TPB = 256;
constexpr int VPT = N / TPB; // 8

#define C1f      14.426950408889634f   // log2(e)/EPS
#define GAM_INIT 22026.465794806718f   // exp(1/EPS), from g0 = ones
#define KF       512.0f                // nu0*N
#define NKF      1536.0f               // nu1*N
#define NF       2048.0f
#define INV_N    (1.0f / 2048.0f)

__global__ void k_max(const float* __restrict__ s, unsigned* __restrict__ ws) {
    __shared__ float red[TPB / 64];
    int idx = blockIdx.x * blockDim.x + threadIdx.x;
    int stride = gridDim.x * blockDim.x;
    float m = 0.f;
    for (int i = idx; i < B * N; i += stride) {
        float x = s[i];
        float xm = x - 1.f;
        m = fmaxf(m, fmaxf(x * x, xm * xm));
    }
#pragma unroll
    for (int off = 32; off; off >>= 1) m = fmaxf(m, __shfl_xor(m, off));
    int lane = threadIdx.x & 63, wid = threadIdx.x >> 6;
    if (lane == 0) red[wid] = m;
    __syncthreads();
    if (threadIdx.x == 0) {
        float mm = red[0];
        for (int w = 1; w < TPB / 64; ++w) mm = fmaxf(mm, red[w]);
        atomicMax(ws, __float_as_uint(mm)); // values >= 0: uint order == float order
    }
}

__launch_bounds__(TPB)
__global__ void k_sink(const float* __restrict__ scores,
                       const unsigned* __restrict__ wsmax,
                       float* __restrict__ out) {
    const int b = blockIdx.x;
    const int tid = threadIdx.x;
    const int lane = tid & 63, wid = tid >> 6;

    __shared__ float lsum[2][TPB / 64]; // [iter parity][wave]

    const float invC = 1.0f / __uint_as_float(*wsmax);
    const float kk = invC * C1f; // exponent scale: E = exp2(-s^2 * kk)

    // Load 8 contiguous scores, build Gibbs kernel entries in registers (once).
    const float4* rv = (const float4*)(scores + b * N + tid * VPT);
    float4 sa = rv[0], sb = rv[1];
    float sv[VPT] = {sa.x, sa.y, sa.z, sa.w, sb.x, sb.y, sb.z, sb.w};
    float E0[VPT], E1[VPT], r[VPT];
#pragma unroll
    for (int i = 0; i < VPT; ++i) {
        float s = sv[i];
        float t = s - 1.f;
        E0[i] = EXP2(-(s * s) * kk);
        E1[i] = EXP2(-(t * t) * kk);
    }

    float g0 = GAM_INIT, g1 = GAM_INIT;

    for (int it = 0; it < MAX_ITER; ++it) {
        const int p = it & 1;
        // f-update + partial T0, two accumulators to break the fma chain.
        float Ta = 0.f, Tb = 0.f;
#pragma unroll
        for (int i = 0; i < VPT; i += 2) {
            float wA = g0 * E0[i]     + g1 * E1[i];
            float wB = g0 * E0[i + 1] + g1 * E1[i + 1];
            r[i]     = RCP(wA);
            r[i + 1] = RCP(wB);
            Ta = fmaf(E0[i], r[i], Ta);
            Tb = fmaf(E0[i + 1], r[i + 1], Tb);
        }
        float T0 = Ta + Tb;
        // block sum reduce (single quantity)
#pragma unroll
        for (int off = 32; off; off >>= 1) T0 += __shfl_xor(T0, off);
        if (lane == 0) lsum[p][wid] = T0;
        __syncthreads();
        T0 = (lsum[p][0] + lsum[p][1]) + (lsum[p][2] + lsum[p][3]);
        // g-update (block-uniform): g0*T0 + g1*T1 = N exactly.
        float d  = fmaf(-g0, T0, NF);      // = g1 * T1
        float g0n = KF * RCP(T0);
        float g1n = NKF * g1 * RCP(d);
        if (g0n == g0 && g1n == g1) break; // bitwise fixed point: rest is identical
        g0 = g0n;
        g1 = g1n;
    }

    // Output: P_a = (g_a/N) * E_a * r   (r is from the last f-update)
    const float u0 = g0 * INV_N, u1 = g1 * INV_N;
    float* o0 = out + b * 2 * N + tid * VPT;
    float* o1 = o0 + N;
    float r0[VPT], r1[VPT];
#pragma unroll
    for (int i = 0; i < VPT; ++i) {
        r0[i] = u0 * E0[i] * r[i];
        r1[i] = u1 * E1[i] * r[i];
    }
    ((float4*)o0)[0] = make_float4(r0[0], r0[1], r0[2], r0[3]);
    ((float4*)o0)[1] = make_float4(r0[4], r0[5], r0[6], r0[7]);
    ((float4*)o1)[0] = make_float4(r1[0], r1[1], r1[2], r1[3]);
    ((float4*)o1)[1] = make_float4(r1[4], r1[5], r1[6], r1[7]);
}

extern "C" void kernel_launch(void* const* d_in, const int* in_sizes, int n_in,
                              void* d_out, int out_size, void* d_ws, size_t ws_size,
                              hipStream_t stream) {
    const float* scores = (const float*)d_in[0];
    float* out = (float*)d_out;
    unsigned* wsu = (unsigned*)d_ws;

    (void)hipMemsetAsync(wsu, 0, sizeof(unsigned), stream);
    k_max<<<512, TPB, 0, stream>>>(scores, wsu);
    k_sink<<<B, TPB, 0, stream>>>(scores, wsu, out);
}

// Round 4
// 64.628 us; speedup vs baseline: 4.4501x; 1.7787x over previous
//
#include <hip/hip_runtime.h>

// Sinkhorn top-K — multiplicative domain, q-only state, one wave per row.
// B=512, N=2048, anchors {0,1}, EPS=0.1, 200 iters.
//
//   q[n]  = E1/E0 = exp2((2 s[n] - 1) * C1f / Cmax)      (precomputed, regs)
//   T0    = sum_n 1/(g0 + g1 q[n])                        (E0 cancels)
//   g0'   = K / T0 ;  g1' = (N-K) g1 / (N - g0 T0)        (identity: g0T0+g1T1=N)
//   P0[n] = g0_fin / (N (g0p + g1p q[n]))                 (g0p,g1p = gammas of last f-update)
//   P1[n] = g1_fin q[n] / (N (g0p + g1p q[n]))

#define EXP2(x) __builtin_amdgcn_exp2f(x)
#define RCP(x)  __builtin_amdgcn_rcpf(x)

constexpr int B = 512;
constexpr int N = 2048;
constexpr int MAX_ITER = 200;
constexpr int VPT = 32; // elements per lane (wave64 covers the row)

#define C1f      14.426950408889634f   // log2(e)/EPS
#define GAM_INIT 22026.465794806718f   // exp(1/EPS), from g = ones
#define KF       512.0f
#define NKF      1536.0f
#define NF       2048.0f
#define INV_N    (1.0f / 2048.0f)

// Canonical wave64 sum all-reduce via DPP (LLVM atomic-optimizer sequence):
// row_shr:1,2,4,8 -> inclusive row prefix; row_bcast15 (rows 1,3),
// row_bcast31 (rows 2,3); lane 63 holds the total; readlane -> uniform.
__device__ __forceinline__ float wave_sum_bcast(float v) {
    float t;
    t = __int_as_float(__builtin_amdgcn_update_dpp(0, __float_as_int(v), 0x111, 0xf, 0xf, false)); v += t;
    t = __int_as_float(__builtin_amdgcn_update_dpp(0, __float_as_int(v), 0x112, 0xf, 0xf, false)); v += t;
    t = __int_as_float(__builtin_amdgcn_update_dpp(0, __float_as_int(v), 0x114, 0xf, 0xf, false)); v += t;
    t = __int_as_float(__builtin_amdgcn_update_dpp(0, __float_as_int(v), 0x118, 0xf, 0xf, false)); v += t;
    t = __int_as_float(__builtin_amdgcn_update_dpp(0, __float_as_int(v), 0x142, 0xa, 0xf, false)); v += t; // row_bcast15
    t = __int_as_float(__builtin_amdgcn_update_dpp(0, __float_as_int(v), 0x143, 0xc, 0xf, false)); v += t; // row_bcast31
    return __int_as_float(__builtin_amdgcn_readlane(__float_as_int(v), 63));
}

__global__ void k_max(const float* __restrict__ s, unsigned* __restrict__ ws) {
    __shared__ float red[4];
    int idx = blockIdx.x * blockDim.x + threadIdx.x;
    int stride = gridDim.x * blockDim.x;
    float m = 0.f;
    const float4* s4 = (const float4*)s;
    for (int i = idx; i < B * N / 4; i += stride) {
        float4 v = s4[i];
        float a = fmaxf(fmaxf(v.x * v.x, v.y * v.y), fmaxf(v.z * v.z, v.w * v.w));
        float bx = v.x - 1.f, by = v.y - 1.f, bz = v.z - 1.f, bw = v.w - 1.f;
        float b = fmaxf(fmaxf(bx * bx, by * by), fmaxf(bz * bz, bw * bw));
        m = fmaxf(m, fmaxf(a, b));
    }
#pragma unroll
    for (int off = 32; off; off >>= 1) m = fmaxf(m, __shfl_xor(m, off));
    int lane = threadIdx.x & 63, wid = threadIdx.x >> 6;
    if (lane == 0) red[wid] = m;
    __syncthreads();
    if (threadIdx.x == 0) {
        float mm = fmaxf(fmaxf(red[0], red[1]), fmaxf(red[2], red[3]));
        atomicMax(ws, __float_as_uint(mm)); // values >= 0: uint order == float order
    }
}

__launch_bounds__(64)
__global__ void k_sink(const float* __restrict__ scores,
                       const unsigned* __restrict__ wsmax,
                       float* __restrict__ out) {
    const int b = blockIdx.x;
    const int l = threadIdx.x;

    const float invC = 1.0f / __uint_as_float(*wsmax);
    const float kk = C1f * invC;
    const float kk2 = 2.0f * kk;

    // Coalesced load: chunk j, lane l -> elements [256j + 4l, +4). Row layout
    // permutation is irrelevant (reductions are permutation-invariant; output
    // is written back to the same slots).
    const float4* src = (const float4*)(scores + b * N);
    float q[VPT];
#pragma unroll
    for (int j = 0; j < 8; ++j) {
        float4 v = src[j * 64 + l];
        q[4 * j + 0] = EXP2(fmaf(v.x, kk2, -kk));
        q[4 * j + 1] = EXP2(fmaf(v.y, kk2, -kk));
        q[4 * j + 2] = EXP2(fmaf(v.z, kk2, -kk));
        q[4 * j + 3] = EXP2(fmaf(v.w, kk2, -kk));
    }

    float g0 = GAM_INIT, g1 = GAM_INIT;
    float g0p = g0, g1p = g1;

    for (int it = 0; it < MAX_ITER; ++it) {
        float Ta = 0.f, Tb = 0.f;
#pragma unroll
        for (int i = 0; i < VPT; i += 4) {
            // pairwise reciprocal: 1/a0 + 1/a1 = (a0+a1) * rcp(a0*a1)
            float a0 = fmaf(g1, q[i], g0);
            float a1 = fmaf(g1, q[i + 1], g0);
            float b0 = fmaf(g1, q[i + 2], g0);
            float b1 = fmaf(g1, q[i + 3], g0);
            Ta = fmaf(a0 + a1, RCP(a0 * a1), Ta);
            Tb = fmaf(b0 + b1, RCP(b0 * b1), Tb);
        }
        float T0 = wave_sum_bcast(Ta + Tb);
        float g0n = KF * RCP(T0);
        float d = fmaf(-g0, T0, NF); // = g1 * T1, no cancellation (-> 1536)
        float g1n = NKF * g1 * RCP(d);
        g0p = g0; g1p = g1;
        if (g0n == g0 && g1n == g1) break; // bitwise fixed point: rest identical
        g0 = g0n; g1 = g1n;
    }

    // Output with final gammas (g0,g1 if break; else post-200-update values)
    // and the gammas used by the last f-update (g0p,g1p).
    const float ug0 = g0 * INV_N, ug1 = g1 * INV_N;
    float4* o0 = (float4*)(out + b * 2 * N);
    float4* o1 = (float4*)(out + b * 2 * N + N);
#pragma unroll
    for (int j = 0; j < 8; ++j) {
        float4 r0v, r1v;
        {
            float rp;
            rp = RCP(fmaf(g1p, q[4 * j + 0], g0p)); r0v.x = ug0 * rp; r1v.x = ug1 * q[4 * j + 0] * rp;
            rp = RCP(fmaf(g1p, q[4 * j + 1], g0p)); r0v.y = ug0 * rp; r1v.y = ug1 * q[4 * j + 1] * rp;
            rp = RCP(fmaf(g1p, q[4 * j + 2], g0p)); r0v.z = ug0 * rp; r1v.z = ug1 * q[4 * j + 2] * rp;
            rp = RCP(fmaf(g1p, q[4 * j + 3], g0p)); r0v.w = ug0 * rp; r1v.w = ug1 * q[4 * j + 3] * rp;
        }
        o0[j * 64 + l] = r0v;
        o1[j * 64 + l] = r1v;
    }
}

extern "C" void kernel_launch(void* const* d_in, const int* in_sizes, int n_in,
                              void* d_out, int out_size, void* d_ws, size_t ws_size,
                              hipStream_t stream) {
    const float* scores = (const float*)d_in[0];
    float* out = (float*)d_out;
    unsigned* wsu = (unsigned*)d_ws;

    (void)hipMemsetAsync(wsu, 0, sizeof(unsigned), stream);
    k_max<<<512, 256, 0, stream>>>(scores, wsu);
    k_sink<<<B, 64, 0, stream>>>(scores, wsu, out);
}

// Round 5
// 33.875 us; speedup vs baseline: 8.4902x; 1.9079x over previous
//
#include <hip/hip_runtime.h>

// Sinkhorn top-K — closed-form reduction to a scalar root-find.
// B=512, N=2048, anchors {0,1}, EPS=0.1.
//
// The 200-iteration Sinkhorn scan converges bitwise to its fixed point
// (verified empirically rounds 3-4: early-exit == full-200, absmax identical).
// At the fixed point everything depends only on rho = g1/g0:
//   q[n]  = exp2((2 s[n] - 1) * C1f / Cmax)
//   S(rho) = sum_n 1/(1 + rho q[n]) = K   (monotone decreasing, convex)
//   P0[n] = (1/N) * 1/(1 + rho q[n])
//   P1[n] = (1/N) * rho q[n]/(1 + rho q[n])
// Newton from rho=0 converges monotonically from below (convexity), ~6-8 iters.

#define EXP2(x) __builtin_amdgcn_exp2f(x)
#define RCP(x)  __builtin_amdgcn_rcpf(x)

constexpr int B = 512;
constexpr int N = 2048;
constexpr int VPT = 32; // elements per lane (wave64 covers the row)
constexpr int NEWTON_MAX = 32;

#define C1f      14.426950408889634f   // log2(e)/EPS
#define KF       512.0f
#define INV_N    (1.0f / 2048.0f)

// Canonical wave64 sum all-reduce via DPP + readlane 63 (validated R3/R4).
__device__ __forceinline__ float wave_sum_bcast(float v) {
    float t;
    t = __int_as_float(__builtin_amdgcn_update_dpp(0, __float_as_int(v), 0x111, 0xf, 0xf, false)); v += t;
    t = __int_as_float(__builtin_amdgcn_update_dpp(0, __float_as_int(v), 0x112, 0xf, 0xf, false)); v += t;
    t = __int_as_float(__builtin_amdgcn_update_dpp(0, __float_as_int(v), 0x114, 0xf, 0xf, false)); v += t;
    t = __int_as_float(__builtin_amdgcn_update_dpp(0, __float_as_int(v), 0x118, 0xf, 0xf, false)); v += t;
    t = __int_as_float(__builtin_amdgcn_update_dpp(0, __float_as_int(v), 0x142, 0xa, 0xf, false)); v += t; // row_bcast15
    t = __int_as_float(__builtin_amdgcn_update_dpp(0, __float_as_int(v), 0x143, 0xc, 0xf, false)); v += t; // row_bcast31
    return __int_as_float(__builtin_amdgcn_readlane(__float_as_int(v), 63));
}

__global__ void k_max(const float* __restrict__ s, unsigned* __restrict__ ws) {
    __shared__ float red[4];
    int idx = blockIdx.x * blockDim.x + threadIdx.x;
    int stride = gridDim.x * blockDim.x;
    float m = 0.f;
    const float4* s4 = (const float4*)s;
    for (int i = idx; i < B * N / 4; i += stride) {
        float4 v = s4[i];
        float a = fmaxf(fmaxf(v.x * v.x, v.y * v.y), fmaxf(v.z * v.z, v.w * v.w));
        float bx = v.x - 1.f, by = v.y - 1.f, bz = v.z - 1.f, bw = v.w - 1.f;
        float b = fmaxf(fmaxf(bx * bx, by * by), fmaxf(bz * bz, bw * bw));
        m = fmaxf(m, fmaxf(a, b));
    }
#pragma unroll
    for (int off = 32; off; off >>= 1) m = fmaxf(m, __shfl_xor(m, off));
    int lane = threadIdx.x & 63, wid = threadIdx.x >> 6;
    if (lane == 0) red[wid] = m;
    __syncthreads();
    if (threadIdx.x == 0) {
        float mm = fmaxf(fmaxf(red[0], red[1]), fmaxf(red[2], red[3]));
        atomicMax(ws, __float_as_uint(mm)); // values >= 0: uint order == float order
    }
}

__launch_bounds__(64)
__global__ void k_sink(const float* __restrict__ scores,
                       const unsigned* __restrict__ wsmax,
                       float* __restrict__ out) {
    const int b = blockIdx.x;
    const int l = threadIdx.x;

    const float invC = 1.0f / __uint_as_float(*wsmax);
    const float kk = C1f * invC;
    const float kk2 = 2.0f * kk;

    // Coalesced load: chunk j, lane l -> elements [256j + 4l, +4).
    const float4* src = (const float4*)(scores + b * N);
    float q[VPT];
#pragma unroll
    for (int j = 0; j < 8; ++j) {
        float4 v = src[j * 64 + l];
        q[4 * j + 0] = EXP2(fmaf(v.x, kk2, -kk));
        q[4 * j + 1] = EXP2(fmaf(v.y, kk2, -kk));
        q[4 * j + 2] = EXP2(fmaf(v.z, kk2, -kk));
        q[4 * j + 3] = EXP2(fmaf(v.w, kk2, -kk));
    }

    // Newton on S(rho) = sum 1/(1+rho q) = K.  D = -S' = sum q/(1+rho q)^2.
    float rho = 0.f;
    for (int it = 0; it < NEWTON_MAX; ++it) {
        float S0 = 0.f, S1 = 0.f, S2 = 0.f, S3 = 0.f;
        float D0 = 0.f, D1 = 0.f, D2 = 0.f, D3 = 0.f;
#pragma unroll
        for (int i = 0; i < VPT; i += 4) {
            float r0 = RCP(fmaf(rho, q[i + 0], 1.f));
            float r1 = RCP(fmaf(rho, q[i + 1], 1.f));
            float r2 = RCP(fmaf(rho, q[i + 2], 1.f));
            float r3 = RCP(fmaf(rho, q[i + 3], 1.f));
            S0 += r0; S1 += r1; S2 += r2; S3 += r3;
            D0 = fmaf(q[i + 0] * r0, r0, D0);
            D1 = fmaf(q[i + 1] * r1, r1, D1);
            D2 = fmaf(q[i + 2] * r2, r2, D2);
            D3 = fmaf(q[i + 3] * r3, r3, D3);
        }
        float S = wave_sum_bcast((S0 + S1) + (S2 + S3));
        float D = wave_sum_bcast((D0 + D1) + (D2 + D3));
        float rho_n = fmaf(S - KF, RCP(D), rho);
        if (rho_n == rho) break; // bitwise converged (uniform across wave)
        rho = rho_n;
    }

    // Output: P0 = (1/N) r, P1 = (1/N) rho q r,  r = 1/(1+rho q).
    const float urho = rho * INV_N;
    float4* o0 = (float4*)(out + b * 2 * N);
    float4* o1 = (float4*)(out + b * 2 * N + N);
#pragma unroll
    for (int j = 0; j < 8; ++j) {
        float4 r0v, r1v;
        float rp;
        rp = RCP(fmaf(rho, q[4 * j + 0], 1.f)); r0v.x = INV_N * rp; r1v.x = urho * q[4 * j + 0] * rp;
        rp = RCP(fmaf(rho, q[4 * j + 1], 1.f)); r0v.y = INV_N * rp; r1v.y = urho * q[4 * j + 1] * rp;
        rp = RCP(fmaf(rho, q[4 * j + 2], 1.f)); r0v.z = INV_N * rp; r1v.z = urho * q[4 * j + 2] * rp;
        rp = RCP(fmaf(rho, q[4 * j + 3], 1.f)); r0v.w = INV_N * rp; r1v.w = urho * q[4 * j + 3] * rp;
        o0[j * 64 + l] = r0v;
        o1[j * 64 + l] = r1v;
    }
}

extern "C" void kernel_launch(void* const* d_in, const int* in_sizes, int n_in,
                              void* d_out, int out_size, void* d_ws, size_t ws_size,
                              hipStream_t stream) {
    const float* scores = (const float*)d_in[0];
    float* out = (float*)d_out;
    unsigned* wsu = (unsigned*)d_ws;

    (void)hipMemsetAsync(wsu, 0, sizeof(unsigned), stream);
    k_max<<<512, 256, 0, stream>>>(scores, wsu);
    k_sink<<<B, 64, 0, stream>>>(scores, wsu, out);
}

// Round 7
// 19.130 us; speedup vs baseline: 15.0341x; 1.7708x over previous
//
#include <hip/hip_runtime.h>

// Sinkhorn top-K — closed-form scalar root-find (validated R5).
//   q[n]   = exp2((2 s[n] - 1) * C1f / Cmax)
//   S(rho) = sum_n 1/(1 + rho q[n]) = K    (monotone decreasing, convex)
//   P0[n]  = (1/N) /(1 + rho q[n]);  P1[n] = (1/N) rho q[n]/(1 + rho q[n])
// Root-find: Newton from rho=0 (monotone from below), upgraded to a guarded
// Halley step (cubic) once the correction term is small; 2-cycle-safe break.
//
// Two graph nodes only: k_max writes 256 partial maxes to d_ws (plain stores,
// every slot written every call -> no memset needed); k_sink reduces them.

#define EXP2(x) __builtin_amdgcn_exp2f(x)
#define RCP(x)  __builtin_amdgcn_rcpf(x)

constexpr int B = 512;
constexpr int N = 2048;
constexpr int VPT = 32;      // elements per lane (wave64 covers a row)
constexpr int IT_MAX = 16;

#define C1f   14.426950408889634f     // log2(e)/EPS
#define KF    512.0f
#define INV_N (1.0f / 2048.0f)

template <int CTRL, int RM>
__device__ __forceinline__ int DPP(int v) {
    return __builtin_amdgcn_update_dpp(0, v, CTRL, RM, 0xf, false);
}

// wave64 max all-reduce (values >= 0; bound-ctrl filler lanes contribute 0).
__device__ __forceinline__ float wave_max_bcast(float v) {
    float t;
    t = __int_as_float(DPP<0x111, 0xf>(__float_as_int(v))); v = fmaxf(v, t);
    t = __int_as_float(DPP<0x112, 0xf>(__float_as_int(v))); v = fmaxf(v, t);
    t = __int_as_float(DPP<0x114, 0xf>(__float_as_int(v))); v = fmaxf(v, t);
    t = __int_as_float(DPP<0x118, 0xf>(__float_as_int(v))); v = fmaxf(v, t);
    t = __int_as_float(DPP<0x142, 0xa>(__float_as_int(v))); v = fmaxf(v, t); // row_bcast15
    t = __int_as_float(DPP<0x143, 0xc>(__float_as_int(v))); v = fmaxf(v, t); // row_bcast31
    return __int_as_float(__builtin_amdgcn_readlane(__float_as_int(v), 63));
}

// three interleaved wave64 sum all-reduces (latency-overlapped DPP chains)
__device__ __forceinline__ void wave_sum3_bcast(float& a, float& b, float& c) {
#define R3(ctrl, rm)                                          \
    {                                                         \
        int ta = DPP<ctrl, rm>(__float_as_int(a));            \
        int tb = DPP<ctrl, rm>(__float_as_int(b));            \
        int tc = DPP<ctrl, rm>(__float_as_int(c));            \
        a += __int_as_float(ta);                              \
        b += __int_as_float(tb);                              \
        c += __int_as_float(tc);                              \
    }
    R3(0x111, 0xf) R3(0x112, 0xf) R3(0x114, 0xf) R3(0x118, 0xf)
    R3(0x142, 0xa) R3(0x143, 0xc)
#undef R3
    a = __int_as_float(__builtin_amdgcn_readlane(__float_as_int(a), 63));
    b = __int_as_float(__builtin_amdgcn_readlane(__float_as_int(b), 63));
    c = __int_as_float(__builtin_amdgcn_readlane(__float_as_int(c), 63));
}

__launch_bounds__(256)
__global__ void k_max(const float* __restrict__ s, float* __restrict__ pmax) {
    __shared__ float red[4];
    const float4* s4 = (const float4*)s;
    const int t = blockIdx.x * 256 + threadIdx.x; // 65536 threads x 4 float4 = 1M floats
    float m = 0.f;
#pragma unroll
    for (int j = 0; j < 4; ++j) {
        float4 v = s4[t + j * 65536];
        float a = fmaxf(fmaxf(v.x * v.x, v.y * v.y), fmaxf(v.z * v.z, v.w * v.w));
        float bx = v.x - 1.f, by = v.y - 1.f, bz = v.z - 1.f, bw = v.w - 1.f;
        float bb = fmaxf(fmaxf(bx * bx, by * by), fmaxf(bz * bz, bw * bw));
        m = fmaxf(m, fmaxf(a, bb));
    }
#pragma unroll
    for (int off = 32; off; off >>= 1) m = fmaxf(m, __shfl_xor(m, off));
    const int lane = threadIdx.x & 63, wid = threadIdx.x >> 6;
    if (lane == 0) red[wid] = m;
    __syncthreads();
    if (threadIdx.x == 0)
        pmax[blockIdx.x] = fmaxf(fmaxf(red[0], red[1]), fmaxf(red[2], red[3]));
}

__launch_bounds__(64)
__global__ void k_sink(const float* __restrict__ scores,
                       const float* __restrict__ pmax,
                       float* __restrict__ out) {
    const int b = blockIdx.x;
    const int l = threadIdx.x;

    // Issue the row loads first (independent of the pmax reduce).
    const float4* src = (const float4*)(scores + b * N);
    float4 vv[8];
#pragma unroll
    for (int j = 0; j < 8; ++j) vv[j] = src[j * 64 + l];

    // Global Cmax from 256 partials (1 float4 per lane + wave max).
    float4 pv = ((const float4*)pmax)[l];
    const float Cmax = wave_max_bcast(fmaxf(fmaxf(pv.x, pv.y), fmaxf(pv.z, pv.w)));
    const float kk = C1f * (1.0f / Cmax);
    const float kk2 = 2.0f * kk;

    float q[VPT];
#pragma unroll
    for (int j = 0; j < 8; ++j) {
        q[4 * j + 0] = EXP2(fmaf(vv[j].x, kk2, -kk));
        q[4 * j + 1] = EXP2(fmaf(vv[j].y, kk2, -kk));
        q[4 * j + 2] = EXP2(fmaf(vv[j].z, kk2, -kk));
        q[4 * j + 3] = EXP2(fmaf(vv[j].w, kk2, -kk));
    }

    // Root-find on S(rho) = K.  r = 1/(1+rho q), u = q r:
    //   S = sum r;  D = -S' = sum u r;  H = S''/2 = sum u^2 r.
    // Newton: rho + W/D.  Halley: rho + W/(D - (W/D) H) — used only when the
    // correction is small (guard avoids far-from-root blowup).
    float rho = 0.f, rho_p = -1.f;
    for (int it = 0; it < IT_MAX; ++it) {
        float S0 = 0.f, S1 = 0.f, D0 = 0.f, D1 = 0.f, H0 = 0.f, H1 = 0.f;
#pragma unroll
        for (int i = 0; i < VPT; i += 2) {
            float r0 = RCP(fmaf(rho, q[i], 1.f));
            float r1 = RCP(fmaf(rho, q[i + 1], 1.f));
            float u0 = q[i] * r0;
            float u1 = q[i + 1] * r1;
            S0 += r0;               S1 += r1;
            D0 = fmaf(u0, r0, D0);  D1 = fmaf(u1, r1, D1);
            H0 = fmaf(u0 * u0, r0, H0); H1 = fmaf(u1 * u1, r1, H1);
        }
        float S = S0 + S1, D = D0 + D1, H = H0 + H1;
        wave_sum3_bcast(S, D, H);
        const float W = S - KF;
        const float tN = W * RCP(D);            // Newton step
        const float corr = tN * H;              // Halley correction term
        float step = (corr < 0.5f * D) ? W * RCP(D - corr) : tN;
        const float rho_n = rho + step;
        if (rho_n == rho || rho_n == rho_p) { rho = rho_n; break; } // fixed pt / 2-cycle
        rho_p = rho;
        rho = rho_n;
    }

    // Output: P0 = (1/N) r, P1 = (1/N) rho q r.
    const float urho = rho * INV_N;
    float4* o0 = (float4*)(out + b * 2 * N);
    float4* o1 = (float4*)(out + b * 2 * N + N);
#pragma unroll
    for (int j = 0; j < 8; ++j) {
        float4 r0v, r1v;
        float rp;
        rp = RCP(fmaf(rho, q[4 * j + 0], 1.f)); r0v.x = INV_N * rp; r1v.x = urho * q[4 * j + 0] * rp;
        rp = RCP(fmaf(rho, q[4 * j + 1], 1.f)); r0v.y = INV_N * rp; r1v.y = urho * q[4 * j + 1] * rp;
        rp = RCP(fmaf(rho, q[4 * j + 2], 1.f)); r0v.z = INV_N * rp; r1v.z = urho * q[4 * j + 2] * rp;
        rp = RCP(fmaf(rho, q[4 * j + 3], 1.f)); r0v.w = INV_N * rp; r1v.w = urho * q[4 * j + 3] * rp;
        o0[j * 64 + l] = r0v;
        o1[j * 64 + l] = r1v;
    }
}

extern "C" void kernel_launch(void* const* d_in, const int* in_sizes, int n_in,
                              void* d_out, int out_size, void* d_ws, size_t ws_size,
                              hipStream_t stream) {
    const float* scores = (const float*)d_in[0];
    float* out = (float*)d_out;
    float* pmax = (float*)d_ws; // 256 floats; fully overwritten by k_max each call

    k_max<<<256, 256, 0, stream>>>(scores, pmax);
    k_sink<<<B, 64, 0, stream>>>(scores, pmax, out);
}